// Round 1
// baseline (390.367 us; speedup 1.0000x reference)
//
#include <hip/hip_runtime.h>

// Shapes fixed by the benchmark's setup_inputs()
#define B_    8
#define N_    65536
#define C_    64
#define H_    256
#define W_    256
#define HW_   (H_ * W_)
#define NPTS  (B_ * N_)

// 1 / (1.0 + PADDING + EPS) = 1 / 1.101
__device__ __constant__ float kInvScale = 0.908265213442325f;

// ---------------------------------------------------------------------------
// Transpose one plane tensor: in [B][C][H*W] f32 -> out [B][H*W][C] f32
// Tile 64(c) x 64(hw) in LDS, padded leading dim to avoid bank conflicts.
// block (64,4) = 256 threads; grid (HW/64, B)
// ---------------------------------------------------------------------------
__global__ __launch_bounds__(256) void transpose_kernel(const float* __restrict__ in,
                                                        float* __restrict__ out) {
    __shared__ float tile[64][65];
    const int b   = blockIdx.y;
    const int hw0 = blockIdx.x * 64;
    const int tx  = threadIdx.x;   // 0..63
    const int ty  = threadIdx.y;   // 0..3

    const float* src = in + (size_t)b * C_ * HW_ + hw0;
#pragma unroll
    for (int i = 0; i < 16; ++i) {
        int c = ty * 16 + i;                       // wave ty loads rows c, coalesced along hw
        tile[c][tx] = src[(size_t)c * HW_ + tx];
    }
    __syncthreads();
    float* dst = out + ((size_t)b * HW_ + hw0) * C_;
#pragma unroll
    for (int i = 0; i < 16; ++i) {
        int r = ty * 16 + i;                       // wave ty writes hw-rows r, coalesced along c
        dst[(size_t)r * C_ + tx] = tile[tx][r];
    }
}

// ---------------------------------------------------------------------------
// Bilinear helpers
// ---------------------------------------------------------------------------
struct Bi { int x0, x1, y0, y1; float wx, wy; };

__device__ __forceinline__ Bi mkbi(float px, float py) {
    // normalize_coordinate: p/1.101 + 0.5, clip [0, 1-1e-3]; then x = pn*(W-1)
    float u = fminf(fmaxf(px * kInvScale + 0.5f, 0.0f), 0.999f);
    float v = fminf(fmaxf(py * kInvScale + 0.5f, 0.0f), 0.999f);
    float x = u * 255.0f;
    float y = v * 255.0f;
    float xf = floorf(x);
    float yf = floorf(y);
    Bi bi;
    bi.wx = x - xf;
    bi.wy = y - yf;
    int x0 = (int)xf, y0 = (int)yf;
    bi.x0 = max(0, min(x0, W_ - 1));
    bi.x1 = min(x0 + 1, W_ - 1);
    bi.y0 = max(0, min(y0, H_ - 1));
    bi.y1 = min(y0 + 1, H_ - 1);
    return bi;
}

// Sample one plane, transposed layout [HW][C]; lane = channel c.
__device__ __forceinline__ float bilin_t(const float* __restrict__ base, Bi bi, int c) {
    float v00 = base[(size_t)(bi.y0 * W_ + bi.x0) * C_ + c];
    float v01 = base[(size_t)(bi.y0 * W_ + bi.x1) * C_ + c];
    float v10 = base[(size_t)(bi.y1 * W_ + bi.x0) * C_ + c];
    float v11 = base[(size_t)(bi.y1 * W_ + bi.x1) * C_ + c];
    float top = v00 + bi.wx * (v01 - v00);
    float bot = v10 + bi.wx * (v11 - v10);
    return top + bi.wy * (bot - top);
}

// Sample one plane, ORIGINAL layout [C][H][W]; lane = channel c (fallback).
__device__ __forceinline__ float bilin_o(const float* __restrict__ base, Bi bi, int c) {
    const float* ch = base + (size_t)c * HW_;
    float v00 = ch[bi.y0 * W_ + bi.x0];
    float v01 = ch[bi.y0 * W_ + bi.x1];
    float v10 = ch[bi.y1 * W_ + bi.x0];
    float v11 = ch[bi.y1 * W_ + bi.x1];
    float top = v00 + bi.wx * (v01 - v00);
    float bot = v10 + bi.wx * (v11 - v10);
    return top + bi.wy * (bot - top);
}

// ---------------------------------------------------------------------------
// Main path: all 3 planes transposed in ws; one pass over points.
// One wave per point; lane = channel. 256 threads = 4 waves/block.
// ---------------------------------------------------------------------------
__global__ __launch_bounds__(256) void sample3_kernel(const float* __restrict__ pts,
                                                      const float* __restrict__ txz,
                                                      const float* __restrict__ txy,
                                                      const float* __restrict__ tyz,
                                                      float* __restrict__ out) {
    const int gtid   = blockIdx.x * blockDim.x + threadIdx.x;
    const int wave   = gtid >> 6;
    const int lane   = threadIdx.x & 63;
    const int nwaves = (gridDim.x * blockDim.x) >> 6;

    for (int p = wave; p < NPTS; p += nwaves) {
        const int b = p >> 16;                    // N_ = 65536
        const size_t pbase = (size_t)p * 3;
        float p0 = pts[pbase + 0];
        float p1 = pts[pbase + 1];
        float p2 = pts[pbase + 2];
        const size_t boff = (size_t)b * HW_ * C_;

        // plane xz: gx=p0, gy=p2 ; xy: gx=p0, gy=p1 ; yz: gx=p1, gy=p2
        float acc = bilin_t(txz + boff, mkbi(p0, p2), lane)
                  + bilin_t(txy + boff, mkbi(p0, p1), lane)
                  + bilin_t(tyz + boff, mkbi(p1, p2), lane);

        out[(size_t)p * C_ + lane] = acc;
    }
}

// Mid tier: one plane at a time from a single transposed buffer; accumulate.
template <bool ACC>
__global__ __launch_bounds__(256) void sample1_kernel(const float* __restrict__ pts,
                                                      const float* __restrict__ tpl,
                                                      float* __restrict__ out,
                                                      int dx, int dy) {
    const int gtid   = blockIdx.x * blockDim.x + threadIdx.x;
    const int wave   = gtid >> 6;
    const int lane   = threadIdx.x & 63;
    const int nwaves = (gridDim.x * blockDim.x) >> 6;

    for (int p = wave; p < NPTS; p += nwaves) {
        const int b = p >> 16;
        const size_t pbase = (size_t)p * 3;
        float p0 = pts[pbase + 0];
        float p1 = pts[pbase + 1];
        float p2 = pts[pbase + 2];
        float gx = (dx == 0) ? p0 : ((dx == 1) ? p1 : p2);
        float gy = (dy == 0) ? p0 : ((dy == 1) ? p1 : p2);
        const size_t boff = (size_t)b * HW_ * C_;
        float s = bilin_t(tpl + boff, mkbi(gx, gy), lane);
        size_t oi = (size_t)p * C_ + lane;
        if (ACC) out[oi] += s; else out[oi] = s;
    }
}

// Last-resort fallback: sample straight from the original [B,C,H,W] layout.
__global__ __launch_bounds__(256) void direct3_kernel(const float* __restrict__ pts,
                                                      const float* __restrict__ fxz,
                                                      const float* __restrict__ fxy,
                                                      const float* __restrict__ fyz,
                                                      float* __restrict__ out) {
    const int gtid   = blockIdx.x * blockDim.x + threadIdx.x;
    const int wave   = gtid >> 6;
    const int lane   = threadIdx.x & 63;
    const int nwaves = (gridDim.x * blockDim.x) >> 6;

    for (int p = wave; p < NPTS; p += nwaves) {
        const int b = p >> 16;
        const size_t pbase = (size_t)p * 3;
        float p0 = pts[pbase + 0];
        float p1 = pts[pbase + 1];
        float p2 = pts[pbase + 2];
        const size_t boff = (size_t)b * C_ * HW_;

        float acc = bilin_o(fxz + boff, mkbi(p0, p2), lane)
                  + bilin_o(fxy + boff, mkbi(p0, p1), lane)
                  + bilin_o(fyz + boff, mkbi(p1, p2), lane);

        out[(size_t)p * C_ + lane] = acc;
    }
}

// ---------------------------------------------------------------------------
extern "C" void kernel_launch(void* const* d_in, const int* in_sizes, int n_in,
                              void* d_out, int out_size, void* d_ws, size_t ws_size,
                              hipStream_t stream) {
    const float* pts = (const float*)d_in[0];
    const float* fxz = (const float*)d_in[1];
    const float* fxy = (const float*)d_in[2];
    const float* fyz = (const float*)d_in[3];
    float* out = (float*)d_out;

    const size_t planeElems = (size_t)B_ * HW_ * C_;       // 33.5M floats
    const size_t planeBytes = planeElems * sizeof(float);  // 134 MB

    const dim3 tb(64, 4);
    const dim3 tg(HW_ / 64, B_);
    const int sampleBlocks = 8192;

    if (ws_size >= 3 * planeBytes) {
        float* txz = (float*)d_ws;
        float* txy = txz + planeElems;
        float* tyz = txy + planeElems;
        transpose_kernel<<<tg, tb, 0, stream>>>(fxz, txz);
        transpose_kernel<<<tg, tb, 0, stream>>>(fxy, txy);
        transpose_kernel<<<tg, tb, 0, stream>>>(fyz, tyz);
        sample3_kernel<<<sampleBlocks, 256, 0, stream>>>(pts, txz, txy, tyz, out);
    } else if (ws_size >= planeBytes) {
        float* t = (float*)d_ws;
        // plane xz: dims (0,2) -> gx=p0, gy=p2
        transpose_kernel<<<tg, tb, 0, stream>>>(fxz, t);
        sample1_kernel<false><<<sampleBlocks, 256, 0, stream>>>(pts, t, out, 0, 2);
        // plane xy: dims (0,1)
        transpose_kernel<<<tg, tb, 0, stream>>>(fxy, t);
        sample1_kernel<true><<<sampleBlocks, 256, 0, stream>>>(pts, t, out, 0, 1);
        // plane yz: dims (1,2)
        transpose_kernel<<<tg, tb, 0, stream>>>(fyz, t);
        sample1_kernel<true><<<sampleBlocks, 256, 0, stream>>>(pts, t, out, 1, 2);
    } else {
        direct3_kernel<<<sampleBlocks, 256, 0, stream>>>(pts, fxz, fxy, fyz, out);
    }
}

// Round 3
// 230.400 us; speedup vs baseline: 1.6943x; 1.6943x over previous
//
#include <hip/hip_runtime.h>
#include <hip/hip_fp16.h>

// Shapes fixed by the benchmark's setup_inputs()
#define B_    8
#define N_    65536
#define C_    64
#define H_    256
#define W_    256
#define HW_   (H_ * W_)
#define NPTS  (B_ * N_)

typedef float f32x2 __attribute__((ext_vector_type(2)));  // native vec for nontemporal store

// 1 / (1.0 + PADDING + EPS) = 1 / 1.101
__device__ __constant__ float kInvScale = 0.908265213442325f;

// ---------------------------------------------------------------------------
// Fused transpose of all 3 planes: f32 [B][C][H*W] -> f16 [B][H*W][C]
// Tile 64(c) x 64(hw) in LDS (padded). block (64,4); grid (HW/64, B, 3).
// Nontemporal input reads: the f32 source is read exactly once — keep it out
// of L3 so the f16 destinations (201 MB total) stay resident for sampling.
// ---------------------------------------------------------------------------
__global__ __launch_bounds__(256) void transpose3_f16_kernel(
    const float* __restrict__ s0, const float* __restrict__ s1,
    const float* __restrict__ s2,
    __half* __restrict__ d0, __half* __restrict__ d1, __half* __restrict__ d2) {
    __shared__ float tile[64][65];
    const float* in;
    __half* out;
    switch (blockIdx.z) {
        case 0:  in = s0; out = d0; break;
        case 1:  in = s1; out = d1; break;
        default: in = s2; out = d2; break;
    }
    const int b   = blockIdx.y;
    const int hw0 = blockIdx.x * 64;
    const int tx  = threadIdx.x;   // 0..63
    const int ty  = threadIdx.y;   // 0..3

    const float* src = in + (size_t)b * C_ * HW_ + hw0;
#pragma unroll
    for (int i = 0; i < 16; ++i) {
        int c = ty * 16 + i;
        tile[c][tx] = __builtin_nontemporal_load(&src[(size_t)c * HW_ + tx]);
    }
    __syncthreads();
    __half2* dst = (__half2*)(out + ((size_t)b * HW_ + hw0) * C_);
    const int c2 = tx & 31;        // channel pair
    const int hh = tx >> 5;        // row half-select
#pragma unroll
    for (int i = 0; i < 8; ++i) {
        int r = ty * 16 + i * 2 + hh;  // wave writes 2 adjacent hw-rows: 256 B contiguous
        dst[r * 32 + c2] = __floats2half2_rn(tile[2 * c2][r], tile[2 * c2 + 1][r]);
    }
}

// ---------------------------------------------------------------------------
// Per-axis bilinear setup. u in [0, 0.999]*255 = [0, 254.745] -> i0 in [0,254],
// i1 = i0+1 <= 255: no clamping needed.
// ---------------------------------------------------------------------------
struct Ax { int i0; float w; };

__device__ __forceinline__ Ax mkax(float p) {
    float u = fminf(fmaxf(p * kInvScale + 0.5f, 0.0f), 0.999f) * 255.0f;
    float f = floorf(u);
    Ax a;
    a.i0 = (int)f;
    a.w  = u - f;
    return a;
}

// Sample one plane (f16 transposed [HW][C]); lane owns channels {2c2, 2c2+1}.
__device__ __forceinline__ float2 bilin2(const __half2* __restrict__ base,
                                         Ax X, Ax Y, int c2) {
    const int t00 = (((Y.i0 << 8) + X.i0) << 5) + c2;  // (y*W+x)*32 + c2
    float2 f00 = __half22float2(base[t00]);
    float2 f01 = __half22float2(base[t00 + 32]);        // x+1
    float2 f10 = __half22float2(base[t00 + 8192]);      // y+1 (256*32)
    float2 f11 = __half22float2(base[t00 + 8224]);
    const float wx = X.w, wy = Y.w;
    float tx0 = f00.x + wx * (f01.x - f00.x);
    float tx1 = f10.x + wx * (f11.x - f10.x);
    float ty0 = f00.y + wx * (f01.y - f00.y);
    float ty1 = f10.y + wx * (f11.y - f10.y);
    float2 r;
    r.x = tx0 + wy * (tx1 - tx0);
    r.y = ty0 + wy * (ty1 - ty0);
    return r;
}

// ---------------------------------------------------------------------------
// Main path: 2 points per wave (half-wave each), half2 per lane.
// Each texel gather = one 128 B cache line per half-wave; out store = one
// contiguous 512 B store per wave.
// ---------------------------------------------------------------------------
__global__ __launch_bounds__(256) void sample3_f16_kernel(
    const float* __restrict__ pts,
    const __half2* __restrict__ txz, const __half2* __restrict__ txy,
    const __half2* __restrict__ tyz, f32x2* __restrict__ out) {
    const int gtid  = blockIdx.x * blockDim.x + threadIdx.x;
    const int wtask = gtid >> 6;
    const int lane  = threadIdx.x & 63;
    const int hh    = lane >> 5;   // which point of the pair
    const int c2    = lane & 31;   // channel pair
    const int nw    = (gridDim.x * blockDim.x) >> 6;

    for (int pp = wtask; pp < NPTS / 2; pp += nw) {
        const int p = pp * 2 + hh;
        const int b = p >> 16;                 // N_ = 65536
        const size_t pb = (size_t)p * 3;
        float p0 = pts[pb + 0];
        float p1 = pts[pb + 1];
        float p2 = pts[pb + 2];
        Ax a0 = mkax(p0), a1 = mkax(p1), a2 = mkax(p2);
        const size_t boff = (size_t)b * (HW_ * 32);

        // xz: (gx,gy)=(p0,p2) ; xy: (p0,p1) ; yz: (p1,p2)
        float2 sxz = bilin2(txz + boff, a0, a2, c2);
        float2 sxy = bilin2(txy + boff, a0, a1, c2);
        float2 syz = bilin2(tyz + boff, a1, a2, c2);
        f32x2 acc;
        acc.x = sxz.x + sxy.x + syz.x;
        acc.y = sxz.y + sxy.y + syz.y;
        __builtin_nontemporal_store(acc, &out[(size_t)p * 32 + c2]);
    }
}

// ===========================================================================
// f32 fallback tiers (unchanged from round 1) — only used if ws is small.
// ===========================================================================
__global__ __launch_bounds__(256) void transpose_kernel(const float* __restrict__ in,
                                                        float* __restrict__ out) {
    __shared__ float tile[64][65];
    const int b   = blockIdx.y;
    const int hw0 = blockIdx.x * 64;
    const int tx  = threadIdx.x;
    const int ty  = threadIdx.y;
    const float* src = in + (size_t)b * C_ * HW_ + hw0;
#pragma unroll
    for (int i = 0; i < 16; ++i) {
        int c = ty * 16 + i;
        tile[c][tx] = src[(size_t)c * HW_ + tx];
    }
    __syncthreads();
    float* dst = out + ((size_t)b * HW_ + hw0) * C_;
#pragma unroll
    for (int i = 0; i < 16; ++i) {
        int r = ty * 16 + i;
        dst[(size_t)r * C_ + tx] = tile[tx][r];
    }
}

struct Bi { int x0, x1, y0, y1; float wx, wy; };

__device__ __forceinline__ Bi mkbi(float px, float py) {
    float u = fminf(fmaxf(px * kInvScale + 0.5f, 0.0f), 0.999f);
    float v = fminf(fmaxf(py * kInvScale + 0.5f, 0.0f), 0.999f);
    float x = u * 255.0f, y = v * 255.0f;
    float xf = floorf(x), yf = floorf(y);
    Bi bi;
    bi.wx = x - xf; bi.wy = y - yf;
    int x0 = (int)xf, y0 = (int)yf;
    bi.x0 = max(0, min(x0, W_ - 1));
    bi.x1 = min(x0 + 1, W_ - 1);
    bi.y0 = max(0, min(y0, H_ - 1));
    bi.y1 = min(y0 + 1, H_ - 1);
    return bi;
}

__device__ __forceinline__ float bilin_t(const float* __restrict__ base, Bi bi, int c) {
    float v00 = base[(size_t)(bi.y0 * W_ + bi.x0) * C_ + c];
    float v01 = base[(size_t)(bi.y0 * W_ + bi.x1) * C_ + c];
    float v10 = base[(size_t)(bi.y1 * W_ + bi.x0) * C_ + c];
    float v11 = base[(size_t)(bi.y1 * W_ + bi.x1) * C_ + c];
    float top = v00 + bi.wx * (v01 - v00);
    float bot = v10 + bi.wx * (v11 - v10);
    return top + bi.wy * (bot - top);
}

__device__ __forceinline__ float bilin_o(const float* __restrict__ base, Bi bi, int c) {
    const float* ch = base + (size_t)c * HW_;
    float v00 = ch[bi.y0 * W_ + bi.x0];
    float v01 = ch[bi.y0 * W_ + bi.x1];
    float v10 = ch[bi.y1 * W_ + bi.x0];
    float v11 = ch[bi.y1 * W_ + bi.x1];
    float top = v00 + bi.wx * (v01 - v00);
    float bot = v10 + bi.wx * (v11 - v10);
    return top + bi.wy * (bot - top);
}

template <bool ACC>
__global__ __launch_bounds__(256) void sample1_kernel(const float* __restrict__ pts,
                                                      const float* __restrict__ tpl,
                                                      float* __restrict__ out,
                                                      int dx, int dy) {
    const int gtid   = blockIdx.x * blockDim.x + threadIdx.x;
    const int wave   = gtid >> 6;
    const int lane   = threadIdx.x & 63;
    const int nwaves = (gridDim.x * blockDim.x) >> 6;
    for (int p = wave; p < NPTS; p += nwaves) {
        const int b = p >> 16;
        const size_t pbase = (size_t)p * 3;
        float p0 = pts[pbase + 0], p1 = pts[pbase + 1], p2 = pts[pbase + 2];
        float gx = (dx == 0) ? p0 : ((dx == 1) ? p1 : p2);
        float gy = (dy == 0) ? p0 : ((dy == 1) ? p1 : p2);
        const size_t boff = (size_t)b * HW_ * C_;
        float s = bilin_t(tpl + boff, mkbi(gx, gy), lane);
        size_t oi = (size_t)p * C_ + lane;
        if (ACC) out[oi] += s; else out[oi] = s;
    }
}

__global__ __launch_bounds__(256) void direct3_kernel(const float* __restrict__ pts,
                                                      const float* __restrict__ fxz,
                                                      const float* __restrict__ fxy,
                                                      const float* __restrict__ fyz,
                                                      float* __restrict__ out) {
    const int gtid   = blockIdx.x * blockDim.x + threadIdx.x;
    const int wave   = gtid >> 6;
    const int lane   = threadIdx.x & 63;
    const int nwaves = (gridDim.x * blockDim.x) >> 6;
    for (int p = wave; p < NPTS; p += nwaves) {
        const int b = p >> 16;
        const size_t pbase = (size_t)p * 3;
        float p0 = pts[pbase + 0], p1 = pts[pbase + 1], p2 = pts[pbase + 2];
        const size_t boff = (size_t)b * C_ * HW_;
        float acc = bilin_o(fxz + boff, mkbi(p0, p2), lane)
                  + bilin_o(fxy + boff, mkbi(p0, p1), lane)
                  + bilin_o(fyz + boff, mkbi(p1, p2), lane);
        out[(size_t)p * C_ + lane] = acc;
    }
}

// ---------------------------------------------------------------------------
extern "C" void kernel_launch(void* const* d_in, const int* in_sizes, int n_in,
                              void* d_out, int out_size, void* d_ws, size_t ws_size,
                              hipStream_t stream) {
    const float* pts = (const float*)d_in[0];
    const float* fxz = (const float*)d_in[1];
    const float* fxy = (const float*)d_in[2];
    const float* fyz = (const float*)d_in[3];
    float* out = (float*)d_out;

    const size_t planeElems  = (size_t)B_ * HW_ * C_;          // 33.5M
    const size_t planeBytesH = planeElems * sizeof(__half);    // 67 MB
    const size_t planeBytesF = planeElems * sizeof(float);     // 134 MB

    const dim3 tb(64, 4);
    const int sampleBlocks = 8192;

    if (ws_size >= 3 * planeBytesH) {
        __half* t0 = (__half*)d_ws;
        __half* t1 = t0 + planeElems;
        __half* t2 = t1 + planeElems;
        transpose3_f16_kernel<<<dim3(HW_ / 64, B_, 3), tb, 0, stream>>>(
            fxz, fxy, fyz, t0, t1, t2);
        sample3_f16_kernel<<<sampleBlocks, 256, 0, stream>>>(
            pts, (const __half2*)t0, (const __half2*)t1, (const __half2*)t2,
            (f32x2*)out);
    } else if (ws_size >= planeBytesF) {
        float* t = (float*)d_ws;
        transpose_kernel<<<dim3(HW_ / 64, B_), tb, 0, stream>>>(fxz, t);
        sample1_kernel<false><<<sampleBlocks, 256, 0, stream>>>(pts, t, out, 0, 2);
        transpose_kernel<<<dim3(HW_ / 64, B_), tb, 0, stream>>>(fxy, t);
        sample1_kernel<true><<<sampleBlocks, 256, 0, stream>>>(pts, t, out, 0, 1);
        transpose_kernel<<<dim3(HW_ / 64, B_), tb, 0, stream>>>(fyz, t);
        sample1_kernel<true><<<sampleBlocks, 256, 0, stream>>>(pts, t, out, 1, 2);
    } else {
        direct3_kernel<<<sampleBlocks, 256, 0, stream>>>(pts, fxz, fxy, fyz, out);
    }
}